// Round 1
// baseline (2511.325 us; speedup 1.0000x reference)
//
#include <hip/hip_runtime.h>
#include <math.h>

// BiLSTM-CRF, fp32 throughout.
// V=50000 B=64 T=256 D=256 H=256 (per dir) C=32
//
// ws layout (floats):
//   w2   : [2][256][1024]     transposed w_hh ([k][j])        524288
//   xg   : [2][64][256][1024] input-gates (+bias)             33554432
//   hcat : [64][256][512]     h_f | h_b (b stored at reversed t)  8388608
//   em   : [64][256][32]      emissions                       524288
// total ~172 MB
//
// d_out: float32[16448] = paths[64][256] (as float) then best_score[64]
// (gamble: harness reads out buffer as float32; if int32, absmax ~1e9 -> flip next round)

// ---------------------------------------------------------------- K0: transpose w_hh
__global__ void k0_transpose(const float* __restrict__ whh_f,
                             const float* __restrict__ whh_b,
                             float* __restrict__ w2)
{
    int idx = blockIdx.x * 256 + threadIdx.x;   // 524288 total
    int dir = idx >> 18;
    int rem = idx & 262143;
    int k = rem >> 10, j = rem & 1023;
    const float* w = dir ? whh_b : whh_f;
    w2[idx] = w[j * 256 + k];
}

// ---------------------------------------------------------------- K1: embed + input GEMM
// out xg[dir][b][t][j] = emb[tok(b,t,dir)] . w_ih[dir][j][:] + b_ih[j]+b_hh[j]
// tile 128 rows x 128 cols, K=256 chunked by 32; thread = 8x8 microtile.
__global__ __launch_bounds__(256) void k1_xgemm(
    const int* __restrict__ sent, const int* __restrict__ lens,
    const float* __restrict__ emb,
    const float* __restrict__ wih_f, const float* __restrict__ wih_b,
    const float* __restrict__ bih_f, const float* __restrict__ bhh_f,
    const float* __restrict__ bih_b, const float* __restrict__ bhh_b,
    float* __restrict__ xg)
{
    const int bid = blockIdx.x;          // 2048 = 2 dir * 128 mt * 8 nt
    const int dir = bid >> 10;
    const int rem = bid & 1023;
    const int mt = rem >> 3, nt = rem & 7;
    const int r0 = mt * 128, j0 = nt * 128;
    const int b = r0 >> 8, t0 = r0 & 255;     // 128 | 256 -> single b per tile
    const float* __restrict__ wih = dir ? wih_b : wih_f;
    const float* __restrict__ bih = dir ? bih_b : bih_f;
    const float* __restrict__ bhh = dir ? bhh_b : bhh_f;

    __shared__ __align__(16) float At[32][132];   // [k][row], pad 132
    __shared__ __align__(16) float Bt[32][132];   // [k][j]
    __shared__ int tok_s[128];

    const int tid = threadIdx.x;
    if (tid < 128) {
        int t = t0 + tid;
        int tt = t;
        if (dir) { int L = lens[b]; if (t < L) tt = L - 1 - t; }
        tok_s[tid] = sent[b * 256 + tt];
    }
    __syncthreads();

    float acc[8][8];
    #pragma unroll
    for (int i = 0; i < 8; ++i)
        #pragma unroll
        for (int j = 0; j < 8; ++j) acc[i][j] = 0.f;

    const int lrow = tid >> 3;   // 0..31
    const int l8 = tid & 7;      // 0..7 (16B each -> 128B/row segment)
    const int tx = tid & 15, ty = tid >> 4;

    for (int kc = 0; kc < 256; kc += 32) {
        #pragma unroll
        for (int it = 0; it < 4; ++it) {
            int row = lrow + it * 32;
            float4 va = *(const float4*)(emb + (size_t)tok_s[row] * 256 + kc + l8 * 4);
            At[l8*4+0][row] = va.x; At[l8*4+1][row] = va.y;
            At[l8*4+2][row] = va.z; At[l8*4+3][row] = va.w;
            float4 vb = *(const float4*)(wih + (size_t)(j0 + row) * 256 + kc + l8 * 4);
            Bt[l8*4+0][row] = vb.x; Bt[l8*4+1][row] = vb.y;
            Bt[l8*4+2][row] = vb.z; Bt[l8*4+3][row] = vb.w;
        }
        __syncthreads();
        #pragma unroll
        for (int k = 0; k < 32; ++k) {
            float4 a0 = *(const float4*)&At[k][ty*8];
            float4 a1 = *(const float4*)&At[k][ty*8+4];
            float4 b0 = *(const float4*)&Bt[k][tx*8];
            float4 b1 = *(const float4*)&Bt[k][tx*8+4];
            float av[8] = {a0.x,a0.y,a0.z,a0.w,a1.x,a1.y,a1.z,a1.w};
            float bv[8] = {b0.x,b0.y,b0.z,b0.w,b1.x,b1.y,b1.z,b1.w};
            #pragma unroll
            for (int i = 0; i < 8; ++i)
                #pragma unroll
                for (int j = 0; j < 8; ++j)
                    acc[i][j] += av[i] * bv[j];
        }
        __syncthreads();
    }

    float bias[8];
    {
        float4 p0 = *(const float4*)(bih + j0 + tx*8);
        float4 p1 = *(const float4*)(bih + j0 + tx*8 + 4);
        float4 q0 = *(const float4*)(bhh + j0 + tx*8);
        float4 q1 = *(const float4*)(bhh + j0 + tx*8 + 4);
        bias[0]=p0.x+q0.x; bias[1]=p0.y+q0.y; bias[2]=p0.z+q0.z; bias[3]=p0.w+q0.w;
        bias[4]=p1.x+q1.x; bias[5]=p1.y+q1.y; bias[6]=p1.z+q1.z; bias[7]=p1.w+q1.w;
    }
    #pragma unroll
    for (int i = 0; i < 8; ++i) {
        int r = r0 + ty*8 + i;
        int t = r & 255;
        float* orow = xg + ((size_t)(dir*64 + b) * 256 + t) * 1024 + j0 + tx*8;
        float4 o0, o1;
        o0.x = acc[i][0]+bias[0]; o0.y = acc[i][1]+bias[1];
        o0.z = acc[i][2]+bias[2]; o0.w = acc[i][3]+bias[3];
        o1.x = acc[i][4]+bias[4]; o1.y = acc[i][5]+bias[5];
        o1.z = acc[i][6]+bias[6]; o1.w = acc[i][7]+bias[7];
        *(float4*)orow = o0;
        *(float4*)(orow + 4) = o1;
    }
}

// ---------------------------------------------------------------- K2: LSTM recurrence
// one WG = 2 sequences of one direction; streams transposed w_hh [k][j] from L2 each step.
// threads: jg = tid&255 -> 4 j-cols, kg = tid>>8 -> 64-k slice; LDS reduction over 4 kg.
__global__ __launch_bounds__(1024) void k2_lstm(
    const float* __restrict__ w2, const float* __restrict__ xg,
    float* __restrict__ hcat)
{
    const int wg = blockIdx.x;          // 64
    const int dir = wg >> 5;
    const int b0 = (wg & 31) * 2;
    const float* __restrict__ w = w2 + (size_t)dir * 262144;
    const float* __restrict__ xg0 = xg + (size_t)(dir*64 + b0) * 262144;
    const float* __restrict__ xg1 = xg0 + 262144;
    float* __restrict__ h0out = hcat + (size_t)b0 * 131072 + dir * 256;
    float* __restrict__ h1out = h0out + 131072;

    __shared__ __align__(16) float hs[2][256];
    __shared__ __align__(16) float cs[2][256];
    __shared__ __align__(16) float red[4][2][1024];

    const int tid = threadIdx.x;
    if (tid < 512) { (&hs[0][0])[tid] = 0.f; (&cs[0][0])[tid] = 0.f; }
    __syncthreads();

    const int jg = tid & 255, j0 = jg * 4;
    const int kg = tid >> 8, kbase = kg * 64;
    const int s  = tid >> 8;        // phase C role (tid<512): s=0/1
    const int jc = tid & 255;

    for (int t = 0; t < 256; ++t) {
        // prefetch xg gate values for phase C (hidden under the w-stream)
        float xpre0 = 0.f, xpre1 = 0.f, xpre2 = 0.f, xpre3 = 0.f;
        if (tid < 512) {
            const float* xp = (s ? xg1 : xg0) + t * 1024 + jc;
            xpre0 = xp[0]; xpre1 = xp[256]; xpre2 = xp[512]; xpre3 = xp[768];
        }
        // phase A: partial gates = w_hh^T slice . h
        float4 acc0 = make_float4(0.f,0.f,0.f,0.f);
        float4 acc1 = make_float4(0.f,0.f,0.f,0.f);
        const float* wp = w + (size_t)kbase * 1024 + j0;
        #pragma unroll 2
        for (int kk = 0; kk < 64; kk += 4) {
            float4 ha = *(const float4*)&hs[0][kbase + kk];   // broadcast read
            float4 hb = *(const float4*)&hs[1][kbase + kk];
            #pragma unroll
            for (int u = 0; u < 4; ++u) {
                float4 wv = *(const float4*)(wp + (size_t)(kk + u) * 1024);
                float hau = (&ha.x)[u], hbu = (&hb.x)[u];
                acc0.x += hau * wv.x; acc0.y += hau * wv.y;
                acc0.z += hau * wv.z; acc0.w += hau * wv.w;
                acc1.x += hbu * wv.x; acc1.y += hbu * wv.y;
                acc1.z += hbu * wv.z; acc1.w += hbu * wv.w;
            }
        }
        *(float4*)&red[kg][0][j0] = acc0;
        *(float4*)&red[kg][1][j0] = acc1;
        __syncthreads();
        // phase BC: reduce + cell update (512 threads: s x 256 j)
        if (tid < 512) {
            float gi = red[0][s][jc]     + red[1][s][jc]     + red[2][s][jc]     + red[3][s][jc]     + xpre0;
            float gf = red[0][s][jc+256] + red[1][s][jc+256] + red[2][s][jc+256] + red[3][s][jc+256] + xpre1;
            float gg = red[0][s][jc+512] + red[1][s][jc+512] + red[2][s][jc+512] + red[3][s][jc+512] + xpre2;
            float go = red[0][s][jc+768] + red[1][s][jc+768] + red[2][s][jc+768] + red[3][s][jc+768] + xpre3;
            float si = 1.f / (1.f + expf(-gi));
            float sf = 1.f / (1.f + expf(-gf));
            float so = 1.f / (1.f + expf(-go));
            float cn = sf * cs[s][jc] + si * tanhf(gg);
            float hn = so * tanhf(cn);
            cs[s][jc] = cn;
            hs[s][jc] = hn;
            (s ? h1out : h0out)[t * 512 + jc] = hn;
        }
        __syncthreads();
    }
}

// ---------------------------------------------------------------- K3: emissions
// em[b][t][c] = [h_f(t) | h_b(rev(t))] . w_out[c] + b_out[c]
__global__ __launch_bounds__(256) void k3_emis(
    const float* __restrict__ hcat, const float* __restrict__ wout,
    const float* __restrict__ bout, const int* __restrict__ lens,
    float* __restrict__ em)
{
    const int b = blockIdx.x >> 3;
    const int tt0 = (blockIdx.x & 7) * 32;
    __shared__ float wsw[512 * 32];    // [k][swizzled c], exactly 64KB
    const int tid = threadIdx.x;
    for (int i = tid; i < 16384; i += 256) {
        int c_ = i >> 9, k_ = i & 511;
        wsw[k_ * 32 + ((k_ + c_) & 31)] = wout[i];   // swizzle: conflict-free rd+wr
    }
    __syncthreads();
    const int c = tid & 31, tq = tid >> 5;
    const int L = lens[b];
    float acc[4];
    const float* hfp[4];
    const float* hbp[4];
    int tv[4];
    #pragma unroll
    for (int i = 0; i < 4; ++i) {
        int t = tt0 + i * 8 + tq;
        tv[i] = t;
        int tr = (t < L) ? (L - 1 - t) : t;
        hfp[i] = hcat + ((size_t)b * 256 + t) * 512;
        hbp[i] = hcat + ((size_t)b * 256 + tr) * 512 + 256;
        acc[i] = bout[c];
    }
    for (int k = 0; k < 256; k += 4) {
        float w0 = wsw[(k+0)*32 + ((k+0+c)&31)];
        float w1 = wsw[(k+1)*32 + ((k+1+c)&31)];
        float w2_ = wsw[(k+2)*32 + ((k+2+c)&31)];
        float w3 = wsw[(k+3)*32 + ((k+3+c)&31)];
        #pragma unroll
        for (int i = 0; i < 4; ++i) {
            float4 h = *(const float4*)(hfp[i] + k);
            acc[i] += h.x*w0 + h.y*w1 + h.z*w2_ + h.w*w3;
        }
        float v0 = wsw[(256+k+0)*32 + ((256+k+0+c)&31)];
        float v1 = wsw[(256+k+1)*32 + ((256+k+1+c)&31)];
        float v2 = wsw[(256+k+2)*32 + ((256+k+2+c)&31)];
        float v3 = wsw[(256+k+3)*32 + ((256+k+3+c)&31)];
        #pragma unroll
        for (int i = 0; i < 4; ++i) {
            float4 h = *(const float4*)(hbp[i] + k);
            acc[i] += h.x*v0 + h.y*v1 + h.z*v2 + h.w*v3;
        }
    }
    #pragma unroll
    for (int i = 0; i < 4; ++i)
        em[((size_t)b * 256 + tv[i]) * 32 + c] = acc[i];
}

// ---------------------------------------------------------------- K4: Viterbi fwd + backtrace (per b)
// exact jnp.argmax tie-break: strict >, ascending prev index.
__global__ __launch_bounds__(256) void k4_viterbi(
    const float* __restrict__ em, const int* __restrict__ lens,
    const float* __restrict__ strans, const float* __restrict__ etrans,
    const float* __restrict__ trans, float* __restrict__ out)
{
    const int b = blockIdx.x;
    __shared__ float em_s[8192];            // 32KB
    __shared__ float trans_t[32 * 33];      // [cur][prev] padded
    __shared__ float score_s[32];
    __shared__ float fin[32];
    __shared__ unsigned char hist[256][32]; // hist[t][cur] = best prev at pos t
    __shared__ unsigned char path[256];
    __shared__ float bs_s;
    const int tid = threadIdx.x;
    for (int i = tid; i < 8192; i += 256) em_s[i] = em[(size_t)b * 8192 + i];
    for (int i = tid; i < 1024; i += 256) {
        int p = i >> 5, cc = i & 31;
        trans_t[cc * 33 + p] = trans[i];
    }
    __syncthreads();
    if (tid < 32) score_s[tid] = strans[tid] + em_s[tid];
    __syncthreads();
    const int c = tid >> 3, pg = tid & 7;   // 32 cur x 8 prev-groups, pg in adjacent lanes
    const int L = lens[b];
    for (int t = 1; t < 256; ++t) {
        float v = -1e30f; int bi = 0;
        #pragma unroll
        for (int i = 0; i < 4; ++i) {
            int p = pg * 4 + i;
            float cand = score_s[p] + trans_t[c * 33 + p];
            if (cand > v) { v = cand; bi = p; }
        }
        #pragma unroll
        for (int off = 4; off >= 1; off >>= 1) {
            float ov = __shfl_down(v, off);
            int oi = __shfl_down(bi, off);
            if (ov > v) { v = ov; bi = oi; }    // strict: tie keeps lower prev
        }
        float ns = 0.f;
        if (pg == 0) {
            hist[t][c] = (unsigned char)bi;
            ns = (t < L) ? (v + em_s[t * 32 + c]) : score_s[c];
        }
        __syncthreads();
        if (pg == 0) score_s[c] = ns;
        __syncthreads();
    }
    if (tid < 32) fin[tid] = score_s[tid] + etrans[tid];
    __syncthreads();
    if (tid == 0) {
        float bv = -1e30f; int bl = 0;
        for (int cc = 0; cc < 32; ++cc)
            if (fin[cc] > bv) { bv = fin[cc]; bl = cc; }   // first-max
        bs_s = bv;
        int tag = bl;
        path[255] = (unsigned char)tag;
        for (int t = 254; t >= 0; --t) {
            if (t < L - 1) tag = hist[t + 1][tag];
            path[t] = (unsigned char)tag;
        }
    }
    __syncthreads();
    out[(size_t)b * 256 + tid] = (float)path[tid];
    if (tid == 0) out[16384 + b] = bs_s;
}

// ---------------------------------------------------------------- launch
extern "C" void kernel_launch(void* const* d_in, const int* in_sizes, int n_in,
                              void* d_out, int out_size, void* d_ws, size_t ws_size,
                              hipStream_t stream)
{
    const int*   sent   = (const int*)  d_in[0];
    const int*   lens   = (const int*)  d_in[1];
    const float* emb    = (const float*)d_in[2];
    const float* wih_f  = (const float*)d_in[3];
    const float* whh_f  = (const float*)d_in[4];
    const float* bih_f  = (const float*)d_in[5];
    const float* bhh_f  = (const float*)d_in[6];
    const float* wih_b  = (const float*)d_in[7];
    const float* whh_b  = (const float*)d_in[8];
    const float* bih_b  = (const float*)d_in[9];
    const float* bhh_b  = (const float*)d_in[10];
    const float* wout   = (const float*)d_in[11];
    const float* bout   = (const float*)d_in[12];
    const float* strans = (const float*)d_in[13];
    const float* etrans = (const float*)d_in[14];
    const float* trans  = (const float*)d_in[15];
    float* out = (float*)d_out;

    float* ws   = (float*)d_ws;
    float* w2   = ws;                    // 524288
    float* xg   = ws + 524288;           // 33554432
    float* hcat = xg + 33554432;         // 8388608
    float* em   = hcat + 8388608;        // 524288

    hipLaunchKernelGGL(k0_transpose, dim3(2048), dim3(256), 0, stream,
                       whh_f, whh_b, w2);
    hipLaunchKernelGGL(k1_xgemm, dim3(2048), dim3(256), 0, stream,
                       sent, lens, emb, wih_f, wih_b, bih_f, bhh_f, bih_b, bhh_b, xg);
    hipLaunchKernelGGL(k2_lstm, dim3(64), dim3(1024), 0, stream,
                       w2, xg, hcat);
    hipLaunchKernelGGL(k3_emis, dim3(512), dim3(256), 0, stream,
                       hcat, wout, bout, lens, em);
    hipLaunchKernelGGL(k4_viterbi, dim3(64), dim3(256), 0, stream,
                       em, lens, strans, etrans, trans, out);
}